// Round 9
// baseline (192.631 us; speedup 1.0000x reference)
//
#include <hip/hip_runtime.h>
#include <math.h>

// Problem constants (B,C,H,W) = (16,20,256,256), fp32 in, 4 fp32 scalars out.
constexpr int Bn = 16, Cn = 20, Hn = 256, Wn = 256;
constexpr int BCn = Bn * Cn;                 // 320 slices
constexpr int HWn = Hn * Wn;                 // 65536 per slice
constexpr int SPLIT = 4;                     // blocks per slice
constexpr int NBLK = BCn * SPLIT;            // 1280 blocks = 5/CU uniform
constexpr int CHUNK = HWn / SPLIT;           // 16384 elems per block
constexpr int TPB = 256;
constexpr int NWAVE = TPB / 64;
constexpr int V4 = CHUNK / (TPB * 4);        // 16 iterations per thread
constexpr int NSLOT = 10;
// ws slots: 0 mass, 1 sum(t*y), 2 sum(t*x), 3 sum(p), 4 sum(p*y), 5 sum(p*x),
//           6 sum(p*(y^2+x^2)), 7 SUM(at*om^2*ln(pt)) [negated in finalize],
//           8 (pred-t)^2, 9 |pred|

#define GLOBAL_AS __attribute__((address_space(1)))
#define LDS_AS    __attribute__((address_space(3)))

__device__ inline float wave_reduce(float v) {
    #pragma unroll
    for (int o = 32; o > 0; o >>= 1) v += __shfl_down(v, o, 64);
    return v;
}

// Async global->LDS DMA, 16 B per lane. HW semantics (m104): each lane's
// 16 B lands at wave-uniform lds_base + lane*16 — matches our linear layout.
__device__ inline void dma16(const float4* g, float4* l) {
    __builtin_amdgcn_global_load_lds((GLOBAL_AS const void*)g,
                                     (LDS_AS void*)l, 16, 0, 0);
}

// Round-9: sessions 1-8 pinned the limiter to the VMEM->VGPR return path
// (~4.4 B/cyc/CU regardless of occupancy/MLP/VALU/memory-source). The
// global_load_lds DMA path sustains ~23 B/cyc/CU on this chip (m97 GEMM
// staging). Double-buffered LDS staging, m97-style 2-barrier loop,
// cross-block overlap from 5 blocks/CU (16 KB LDS each).
__global__ __launch_bounds__(TPB) void partials_kernel(
        const float* __restrict__ pred, const float* __restrict__ target,
        float* __restrict__ ws) {
    __shared__ float4 sbuf[2][2][TPB];       // [buf][stream][slot], 16 KB
    const int blk = blockIdx.x;
    const int bc = blk >> 2;                 // / SPLIT
    const int chunk = blk & (SPLIT - 1);
    const long long base = (long long)bc * HWn + (long long)chunk * CHUNK;
    const float4* __restrict__ p4 = (const float4*)(pred + base);
    const float4* __restrict__ t4 = (const float4*)(target + base);
    const int tid = threadIdx.x;
    const int wslot = (tid >> 6) << 6;       // wave-uniform LDS slot base

    // accumulators (x/y-separable form)
    float st[4] = {0.f, 0.f, 0.f, 0.f};     // per-j sum of t
    float sp[4] = {0.f, 0.f, 0.f, 0.f};     // per-j sum of p
    float sty = 0.f, spy = 0.f, spyy = 0.f; // y-weighted sums
    float foc = 0.f, sq = 0.f, ab = 0.f;

    // iter k covers chunk elements [k*1024,(k+1)*1024): 4 rows.
    // x thread-invariant; y = chunk*64 + (tid>>6) + 4k.
    const float x0 = (float)((tid & 63) << 2);
    float y = (float)((chunk << 6) + (tid >> 6));

    // prime buffer 0
    dma16(p4 + tid, &sbuf[0][0][wslot]);
    dma16(t4 + tid, &sbuf[0][1][wslot]);

    for (int k = 0; k < V4; k++) {
        const int buf = k & 1;
        if (k + 1 < V4) {                    // stage next into other buffer
            dma16(p4 + (k + 1) * TPB + tid, &sbuf[buf ^ 1][0][wslot]);
            dma16(t4 + (k + 1) * TPB + tid, &sbuf[buf ^ 1][1][wslot]);
        }
        __syncthreads();                     // all waves' stage(k) complete
        const float4 pa = sbuf[buf][0][tid];
        const float4 ta = sbuf[buf][1][tid];
        __syncthreads();                     // done reading before re-stage

        const float yy = y * y;
        const float pvals[4] = {pa.x, pa.y, pa.z, pa.w};
        const float tvals[4] = {ta.x, ta.y, ta.z, ta.w};
        float pj[4];
        #pragma unroll
        for (int j = 0; j < 4; j++) {
            const float v = pvals[j];
            const float t = tvals[j];
            const float e = __expf(-v);                      // e^{-v}
            const float p = __builtin_amdgcn_rcpf(1.0f + e); // sigmoid
            pj[j] = p;
            // focal: at*om^2 = (pos ? 0.5-0.5p : 0.8660254*p)^2
            //        ln(pt)  = lp - (pos ? 0 : v)
            const bool pos = (t > 0.5f);
            const float lp = __logf(p);
            const float lpt = pos ? lp : lp - v;
            const float q = pos ? fmaf(-0.5f, p, 0.5f) : 0.8660254f * p;
            foc = fmaf(q * q, lpt, foc);                     // negate later
            // sparsity
            const float d = v - t;
            sq = fmaf(d, d, sq);
            ab += fabsf(v);
            // separable partial sums
            st[j] += t;
            sp[j] += p;
        }
        const float s_t = (tvals[0] + tvals[1]) + (tvals[2] + tvals[3]);
        const float s_p = (pj[0] + pj[1]) + (pj[2] + pj[3]);
        sty  = fmaf(s_t, y,  sty);
        spy  = fmaf(s_p, y,  spy);
        spyy = fmaf(s_p, yy, spyy);
        y += 4.0f;
    }

    // per-thread epilogue: expand per-j sums with x weights
    const float x1 = x0 + 1.f, x2 = x0 + 2.f, x3 = x0 + 3.f;
    const float mass = (st[0] + st[1]) + (st[2] + st[3]);
    const float Sp   = (sp[0] + sp[1]) + (sp[2] + sp[3]);
    float stx  = x0 * st[0];
    stx = fmaf(x1, st[1], stx); stx = fmaf(x2, st[2], stx); stx = fmaf(x3, st[3], stx);
    float spx  = x0 * sp[0];
    spx = fmaf(x1, sp[1], spx); spx = fmaf(x2, sp[2], spx); spx = fmaf(x3, sp[3], spx);
    float spxx = (x0 * x0) * sp[0];
    spxx = fmaf(x1 * x1, sp[1], spxx);
    spxx = fmaf(x2 * x2, sp[2], spxx);
    spxx = fmaf(x3 * x3, sp[3], spxx);
    const float sprr = spyy + spxx;

    float acc[NSLOT] = {mass, sty, stx, Sp, spy, spx, sprr, foc, sq, ab};

    __shared__ float lds[NWAVE][NSLOT];
    const int lane = tid & 63, wave = tid >> 6;
    #pragma unroll
    for (int k = 0; k < NSLOT; k++) {
        const float r = wave_reduce(acc[k]);
        if (lane == 0) lds[wave][k] = r;
    }
    __syncthreads();
    if (tid < NSLOT) {
        float s = 0.f;
        #pragma unroll
        for (int w = 0; w < NWAVE; w++) s += lds[w][tid];
        ws[blk * NSLOT + tid] = s;
    }
}

__global__ __launch_bounds__(512) void finalize_kernel(
        const float* __restrict__ ws, float* __restrict__ out) {
    const int tid = threadIdx.x;

    // Per-(b,c) concentration term (threads 0..319)
    float conc_sum = 0.f, nvalid = 0.f;
    if (tid < BCn) {
        float mass = 0, sty = 0, stx = 0, sp = 0, spy = 0, spx = 0, sprr = 0;
        for (int s = 0; s < SPLIT; s++) {
            const float* w = ws + (size_t)(tid * SPLIT + s) * NSLOT;
            mass += w[0]; sty += w[1]; stx += w[2]; sp += w[3];
            spy  += w[4]; spx += w[5]; sprr += w[6];
        }
        const bool valid = mass > 0.f;
        const float sm = valid ? mass : 1.0f;
        const float cy = sty / sm, cx = stx / sm;
        const float pdsq = sprr - 2.f * cy * spy - 2.f * cx * spx
                         + (cy * cy + cx * cx) * sp;
        conc_sum = valid ? (pdsq / (float)HWn) : 0.f;   // per-sample mean
        nvalid   = valid ? 1.f : 0.f;
    }

    // Global focal / sparsity sums over all partial blocks
    float foc = 0.f, sq = 0.f, ab = 0.f;
    for (int blk = tid; blk < NBLK; blk += 512) {
        const float* w = ws + (size_t)blk * NSLOT;
        foc += w[7]; sq += w[8]; ab += w[9];
    }

    __shared__ float lds[8][5];
    const int lane = tid & 63, wave = tid >> 6;
    float vals[5] = {conc_sum, nvalid, foc, sq, ab};
    #pragma unroll
    for (int k = 0; k < 5; k++) {
        const float r = wave_reduce(vals[k]);
        if (lane == 0) lds[wave][k] = r;
    }
    __syncthreads();

    if (tid == 0) {
        float tot[5];
        #pragma unroll
        for (int k = 0; k < 5; k++) {
            float s = 0.f;
            #pragma unroll
            for (int w = 0; w < 8; w++) s += lds[w][k];
            tot[k] = s;
        }
        const float NTOT = (float)Bn * Cn * Hn * Wn;   // 20971520
        const float focal = -tot[2] / NTOT;            // slot7 = +sum(at*om^2*ln pt)
        const float sparsity = tot[3] / NTOT + tot[4] / NTOT;
        const float concentration =
            (tot[1] > 0.f) ? (tot[0] / fmaxf(tot[1], 1.f)) : 0.f;
        const float total = 1.0f * focal + 0.8f * sparsity + 1.5f * concentration;
        out[0] = total;
        out[1] = focal;
        out[2] = sparsity;
        out[3] = concentration;
    }
}

extern "C" void kernel_launch(void* const* d_in, const int* in_sizes, int n_in,
                              void* d_out, int out_size, void* d_ws, size_t ws_size,
                              hipStream_t stream) {
    const float* pred   = (const float*)d_in[0];
    const float* target = (const float*)d_in[1];
    float* out = (float*)d_out;
    float* ws  = (float*)d_ws;   // needs NBLK*NSLOT*4 = 51.2 KB

    partials_kernel<<<NBLK, TPB, 0, stream>>>(pred, target, ws);
    finalize_kernel<<<1, 512, 0, stream>>>(ws, out);
}

// Round 10
// 189.593 us; speedup vs baseline: 1.0160x; 1.0160x over previous
//
#include <hip/hip_runtime.h>
#include <math.h>

// Problem constants (B,C,H,W) = (16,20,256,256), fp32 in, 4 fp32 scalars out.
constexpr int Bn = 16, Cn = 20, Hn = 256, Wn = 256;
constexpr int BCn = Bn * Cn;                 // 320 slices
constexpr int HWn = Hn * Wn;                 // 65536 per slice
constexpr int SPLIT = 8;                     // blocks per slice
constexpr int NBLK = BCn * SPLIT;            // 2560 blocks
constexpr int CHUNK = HWn / SPLIT;           // 8192 elems per block
constexpr int TPB = 256;
constexpr int NWAVE = TPB / 64;
constexpr int V4 = CHUNK / (TPB * 4);        // 8 float4 per thread
constexpr int NSLOT = 10;
// ws slots: 0 mass, 1 sum(t*y), 2 sum(t*x), 3 sum(p), 4 sum(p*y), 5 sum(p*x),
//           6 sum(p*(y^2+x^2)), 7 SUM(at*om^2*ln(pt)) [negated in finalize],
//           8 (pred-t)^2, 9 |pred|
//
// Session conclusion (rounds 1-9): 9 structures (occ 19-75%, MLP 2-16,
// VGPR-return vs global_load_lds DMA, TPB 256/512/1024, VALU -40%) all land
// 64-73 us. Floor = 168 MB through the per-CU ingest path (~10 B/cyc/CU)
// at the DVFS-governed effective clock; VALUBusy ledger closes at ~1 GHz.
// Bytes are algorithmically minimal (each input element needed once, no
// reuse). This file locks in the best-measured structure: round-5 staging
// (256T, SPLIT=8, depth-1 rotating prefetch, no launch_bounds clamp) +
// round-8 separable-sum compute.

__device__ inline float wave_reduce(float v) {
    #pragma unroll
    for (int o = 32; o > 0; o >>= 1) v += __shfl_down(v, o, 64);
    return v;
}

__global__ __launch_bounds__(TPB) void partials_kernel(
        const float* __restrict__ pred, const float* __restrict__ target,
        float* __restrict__ ws) {
    const int blk = blockIdx.x;
    const int bc = blk >> 3;                 // / SPLIT
    const int chunk = blk & (SPLIT - 1);
    const long long base = (long long)bc * HWn + (long long)chunk * CHUNK;
    const float4* __restrict__ p4 = (const float4*)(pred + base);
    const float4* __restrict__ t4 = (const float4*)(target + base);
    const int tid = threadIdx.x;

    // accumulators (x/y-separable form)
    float st[4] = {0.f, 0.f, 0.f, 0.f};     // per-j sum of t
    float sp[4] = {0.f, 0.f, 0.f, 0.f};     // per-j sum of p
    float sty = 0.f, spy = 0.f, spyy = 0.f; // y-weighted sums
    float foc = 0.f, sq = 0.f, ab = 0.f;

    // Element index in slice = chunk*CHUNK + tid*4 + i*1024.
    // 1024 is a multiple of W=256 -> x thread-invariant, y steps by 4.
    const int e_base = chunk * CHUNK + tid * 4;
    const float x0 = (float)(e_base & 255);
    float y = (float)(e_base >> 8);

    // depth-1 rotating prefetch (round-5 structure: best measured, no spill)
    float4 pc = p4[tid];
    float4 tc = t4[tid];

    #pragma unroll
    for (int i = 0; i < V4; i++) {
        float4 pn, tn;
        if (i + 1 < V4) {
            pn = p4[(i + 1) * TPB + tid];
            tn = t4[(i + 1) * TPB + tid];
        }
        const float yy = y * y;
        const float pvals[4] = {pc.x, pc.y, pc.z, pc.w};
        const float tvals[4] = {tc.x, tc.y, tc.z, tc.w};
        float pj[4];
        #pragma unroll
        for (int j = 0; j < 4; j++) {
            const float v = pvals[j];
            const float t = tvals[j];
            const float e = __expf(-v);                      // e^{-v}
            const float p = __builtin_amdgcn_rcpf(1.0f + e); // sigmoid
            pj[j] = p;
            // focal: at*om^2 = (pos ? 0.5-0.5p : 0.8660254*p)^2
            //        ln(pt)  = lp - (pos ? 0 : v);  (1-p = e^{-v} p)
            const bool pos = (t > 0.5f);
            const float lp = __logf(p);
            const float lpt = pos ? lp : lp - v;
            const float q = pos ? fmaf(-0.5f, p, 0.5f) : 0.8660254f * p;
            foc = fmaf(q * q, lpt, foc);                     // negate later
            // sparsity
            const float d = v - t;
            sq = fmaf(d, d, sq);
            ab += fabsf(v);
            // separable partial sums
            st[j] += t;
            sp[j] += p;
        }
        const float s_t = (tvals[0] + tvals[1]) + (tvals[2] + tvals[3]);
        const float s_p = (pj[0] + pj[1]) + (pj[2] + pj[3]);
        sty  = fmaf(s_t, y,  sty);
        spy  = fmaf(s_p, y,  spy);
        spyy = fmaf(s_p, yy, spyy);
        y += 4.0f;
        if (i + 1 < V4) { pc = pn; tc = tn; }
    }

    // per-thread epilogue: expand per-j sums with x weights
    const float x1 = x0 + 1.f, x2 = x0 + 2.f, x3 = x0 + 3.f;
    const float mass = (st[0] + st[1]) + (st[2] + st[3]);
    const float Sp   = (sp[0] + sp[1]) + (sp[2] + sp[3]);
    float stx  = x0 * st[0];
    stx = fmaf(x1, st[1], stx); stx = fmaf(x2, st[2], stx); stx = fmaf(x3, st[3], stx);
    float spx  = x0 * sp[0];
    spx = fmaf(x1, sp[1], spx); spx = fmaf(x2, sp[2], spx); spx = fmaf(x3, sp[3], spx);
    float spxx = (x0 * x0) * sp[0];
    spxx = fmaf(x1 * x1, sp[1], spxx);
    spxx = fmaf(x2 * x2, sp[2], spxx);
    spxx = fmaf(x3 * x3, sp[3], spxx);
    const float sprr = spyy + spxx;

    float acc[NSLOT] = {mass, sty, stx, Sp, spy, spx, sprr, foc, sq, ab};

    __shared__ float lds[NWAVE][NSLOT];
    const int lane = tid & 63, wave = tid >> 6;
    #pragma unroll
    for (int k = 0; k < NSLOT; k++) {
        const float r = wave_reduce(acc[k]);
        if (lane == 0) lds[wave][k] = r;
    }
    __syncthreads();
    if (tid < NSLOT) {
        float s = 0.f;
        #pragma unroll
        for (int w = 0; w < NWAVE; w++) s += lds[w][tid];
        ws[blk * NSLOT + tid] = s;
    }
}

__global__ __launch_bounds__(512) void finalize_kernel(
        const float* __restrict__ ws, float* __restrict__ out) {
    const int tid = threadIdx.x;

    // Per-(b,c) concentration term (threads 0..319)
    float conc_sum = 0.f, nvalid = 0.f;
    if (tid < BCn) {
        float mass = 0, sty = 0, stx = 0, sp = 0, spy = 0, spx = 0, sprr = 0;
        for (int s = 0; s < SPLIT; s++) {
            const float* w = ws + (size_t)(tid * SPLIT + s) * NSLOT;
            mass += w[0]; sty += w[1]; stx += w[2]; sp += w[3];
            spy  += w[4]; spx += w[5]; sprr += w[6];
        }
        const bool valid = mass > 0.f;
        const float sm = valid ? mass : 1.0f;
        const float cy = sty / sm, cx = stx / sm;
        const float pdsq = sprr - 2.f * cy * spy - 2.f * cx * spx
                         + (cy * cy + cx * cx) * sp;
        conc_sum = valid ? (pdsq / (float)HWn) : 0.f;   // per-sample mean
        nvalid   = valid ? 1.f : 0.f;
    }

    // Global focal / sparsity sums over all partial blocks
    float foc = 0.f, sq = 0.f, ab = 0.f;
    for (int blk = tid; blk < NBLK; blk += 512) {
        const float* w = ws + (size_t)blk * NSLOT;
        foc += w[7]; sq += w[8]; ab += w[9];
    }

    __shared__ float lds[8][5];
    const int lane = tid & 63, wave = tid >> 6;
    float vals[5] = {conc_sum, nvalid, foc, sq, ab};
    #pragma unroll
    for (int k = 0; k < 5; k++) {
        const float r = wave_reduce(vals[k]);
        if (lane == 0) lds[wave][k] = r;
    }
    __syncthreads();

    if (tid == 0) {
        float tot[5];
        #pragma unroll
        for (int k = 0; k < 5; k++) {
            float s = 0.f;
            #pragma unroll
            for (int w = 0; w < 8; w++) s += lds[w][k];
            tot[k] = s;
        }
        const float NTOT = (float)Bn * Cn * Hn * Wn;   // 20971520
        const float focal = -tot[2] / NTOT;            // slot7 = +sum(at*om^2*ln pt)
        const float sparsity = tot[3] / NTOT + tot[4] / NTOT;
        const float concentration =
            (tot[1] > 0.f) ? (tot[0] / fmaxf(tot[1], 1.f)) : 0.f;
        const float total = 1.0f * focal + 0.8f * sparsity + 1.5f * concentration;
        out[0] = total;
        out[1] = focal;
        out[2] = sparsity;
        out[3] = concentration;
    }
}

extern "C" void kernel_launch(void* const* d_in, const int* in_sizes, int n_in,
                              void* d_out, int out_size, void* d_ws, size_t ws_size,
                              hipStream_t stream) {
    const float* pred   = (const float*)d_in[0];
    const float* target = (const float*)d_in[1];
    float* out = (float*)d_out;
    float* ws  = (float*)d_ws;   // needs NBLK*NSLOT*4 = 102.4 KB

    partials_kernel<<<NBLK, TPB, 0, stream>>>(pred, target, ws);
    finalize_kernel<<<1, 512, 0, stream>>>(ws, out);
}